// Round 6
// baseline (308.566 us; speedup 1.0000x reference)
//
#include <hip/hip_runtime.h>
#include <math.h>

#define H_HEADS 33
#define C_CH    16
#define HC      528      // H_HEADS * C_CH
#define JG      11       // head groups of 3 (48 cols each) for h
#define JGT     13       // + 2 groups: att_src logits, att_dst logits
#define F_IN    128
#define NEG_SLOPE 0.2f

typedef short  bf16x8  __attribute__((ext_vector_type(8)));
typedef float  floatx4 __attribute__((ext_vector_type(4)));

__device__ inline unsigned short f2bf(float f) {   // RNE float->bf16
    unsigned int u = __float_as_uint(f);
    unsigned int r = u + 0x7fffu + ((u >> 16) & 1u);
    return (unsigned short)(r >> 16);
}
__device__ inline float bflo(unsigned int u) {
    return __uint_as_float(u << 16);
}
__device__ inline float bfhi(unsigned int u) {
    return __uint_as_float(u & 0xffff0000u);
}

// ---------------------------------------------------------------------------
// K0: Wt[0..527] = bf16(W^T); rows 528..623 = attention-logit GEMM columns
// (row 528+h: Ws[k,h]=sum_c W[k][h*16+c]*att_src[h][c]; 576+h likewise with
// att_dst). Also zeroes hist_s/hist_d and out (folds away two memsets).
// ---------------------------------------------------------------------------
#define PW1 (F_IN * HC)        // 67584
#define PW2 (PW1 + 96 * F_IN)  // 79872
__global__ void prep_kernel(const float* __restrict__ W,
                            const float* __restrict__ att_src,
                            const float* __restrict__ att_dst,
                            unsigned short* __restrict__ Wt,
                            int4* __restrict__ z1, int nz1,
                            float4* __restrict__ z2, int nz2)
{
    int g = blockIdx.x * blockDim.x + threadIdx.x;
    if (g < PW1) {
        int k = g / HC, n = g % HC;
        Wt[n * F_IN + k] = f2bf(W[g]);
    } else if (g < PW2) {
        int gg = g - PW1;
        int nl = gg >> 7, k = gg & 127;
        int grp = nl / 48, h = nl % 48;
        float v = 0.f;
        if (h < H_HEADS) {
            const float* att = grp ? att_dst : att_src;
            const float* wr  = W + (size_t)k * HC + h * C_CH;
            #pragma unroll
            for (int c = 0; c < C_CH; ++c) v += wr[c] * att[h * C_CH + c];
        }
        Wt[(size_t)(HC + nl) * F_IN + k] = f2bf(v);
    } else {
        int z = g - PW2;
        if (z < nz1)            z1[z]       = make_int4(0, 0, 0, 0);
        else if (z - nz1 < nz2) z2[z - nz1] = make_float4(0.f, 0.f, 0.f, 0.f);
    }
}

// ---------------------------------------------------------------------------
// K1: h = x @ W via MFMA 16x16x32 bf16 — NO LDS, NO BARRIERS. Wt (160KB) is
// L1/L2-resident, so each lane loads its B fragment directly from global at
// the exact offset it used to read from the LDS tile; A fragments load from
// x per-lane with in-register f32->bf16 convert. The 26 barriers/block and
// all staging vanish; waves run free (lesson: don't LDS-stage cache-fit
// data). Groups 0..10 -> hb column-blocked [j][row][48]; 11 -> a_src;
// 12 -> a_dstc.
// ---------------------------------------------------------------------------
__global__ __launch_bounds__(256, 4) void gemm_att_kernel(
    const float* __restrict__ x, const unsigned short* __restrict__ Wt,
    unsigned short* __restrict__ hb,
    float* __restrict__ a_src, float* __restrict__ a_dstc, int N)
{
    const int tid  = threadIdx.x;
    const int lane = tid & 63;
    const int wave = tid >> 6;
    const int lm   = lane & 15;
    const int kc   = lane >> 4;
    const int m0   = blockIdx.x * 64;
    const size_t segN = (size_t)N * 48;

    // A fragments: per-lane direct load from x (clamp OOB rows to a valid
    // row; their outputs are discarded by the row<N store guards)
    const int arow = m0 + wave * 16 + lm;
    const float* xr = x + (size_t)(arow < N ? arow : N - 1) * F_IN;
    bf16x8 afrag[4];
    #pragma unroll
    for (int ks = 0; ks < 4; ++ks) {
        float4 v0 = *(const float4*)&xr[ks * 32 + kc * 8];
        float4 v1 = *(const float4*)&xr[ks * 32 + kc * 8 + 4];
        bf16x8 a;
        a[0] = (short)f2bf(v0.x); a[1] = (short)f2bf(v0.y);
        a[2] = (short)f2bf(v0.z); a[3] = (short)f2bf(v0.w);
        a[4] = (short)f2bf(v1.x); a[5] = (short)f2bf(v1.y);
        a[6] = (short)f2bf(v1.z); a[7] = (short)f2bf(v1.w);
        afrag[ks] = a;
    }

    #pragma unroll 1
    for (int j = 0; j < JGT; ++j) {
        const unsigned short* wb = Wt + (size_t)j * 48 * F_IN;
        floatx4 acc[3] = {};
        #pragma unroll
        for (int ks = 0; ks < 4; ++ks) {
            #pragma unroll
            for (int t = 0; t < 3; ++t) {
                bf16x8 b = *(const bf16x8*)&wb[(t * 16 + lm) * F_IN + ks * 32 + kc * 8];
                acc[t] = __builtin_amdgcn_mfma_f32_16x16x32_bf16(afrag[ks], b, acc[t], 0, 0, 0);
            }
        }
        // C/D layout: col = lane&15, row = (lane>>4)*4 + reg
        #pragma unroll
        for (int t = 0; t < 3; ++t) {
            #pragma unroll
            for (int rr = 0; rr < 4; ++rr) {
                const int row = m0 + wave * 16 + kc * 4 + rr;
                if (row >= N) continue;
                if (j < JG) {
                    hb[(size_t)j * segN + (size_t)row * 48 + t * 16 + lm] =
                        f2bf(acc[t][rr]);
                } else {
                    const int col = t * 16 + lm;
                    if (col < H_HEADS) {
                        float* dstp = (j == JG) ? a_src : a_dstc;
                        dstp[(size_t)row * H_HEADS + col] = acc[t][rr];
                    }
                }
            }
        }
    }
}

// ---------------------------------------------------------------------------
// Counting sort of edges (incl. self loops) by src (for aggregate's h gather
// locality) AND by dst (for atomic-free denom).
// ---------------------------------------------------------------------------
__global__ void hist_kernel(const int* __restrict__ ei,
                            int* __restrict__ hist_s, int* __restrict__ hist_d,
                            int E, int Et)
{
    int g = blockIdx.x * blockDim.x + threadIdx.x;
    if (g >= Et) return;
    int src, dst;
    if (g < E) { src = ei[g]; dst = ei[E + g]; }
    else       { src = dst = g - E; }
    atomicAdd(&hist_s[src], 1);
    atomicAdd(&hist_d[dst], 1);
}

// exclusive scan, 16 elems/thread; grid=2: block0 scans hist_s->cur_s,
// block1 scans hist_d->cur_d+off_d (the two scans run concurrently).
#define VPT 16
__global__ __launch_bounds__(1024) void scan_kernel(
    const int* __restrict__ hist_s, int* __restrict__ cur_s,
    const int* __restrict__ hist_d, int* __restrict__ cur_d,
    int* __restrict__ off_d, int n)
{
    const int* hist = blockIdx.x ? hist_d : hist_s;
    int* o0 = blockIdx.x ? cur_d : cur_s;
    int* o1 = blockIdx.x ? off_d : (int*)nullptr;

    __shared__ int warp_sums[16];
    __shared__ int s_carry;
    const int tid  = threadIdx.x;
    const int lane = tid & 63, wid = tid >> 6;
    if (tid == 0) s_carry = 0;
    __syncthreads();
    const int nC = (n + VPT - 1) / VPT;
    for (int base = 0; base < nC; base += 1024) {
        int iC = base + tid;
        int v[VPT];
        bool full = (iC * VPT + VPT <= n);
        if (full) {
            #pragma unroll
            for (int qq = 0; qq < VPT / 4; ++qq)
                *(int4*)&v[qq * 4] = ((const int4*)hist)[iC * (VPT / 4) + qq];
        } else {
            #pragma unroll
            for (int k = 0; k < VPT; ++k)
                v[k] = (iC * VPT + k < n) ? hist[iC * VPT + k] : 0;
        }
        int tsum = 0;
        #pragma unroll
        for (int k = 0; k < VPT; ++k) tsum += v[k];
        int s = tsum;
        #pragma unroll
        for (int dd = 1; dd < 64; dd <<= 1) {
            int t = __shfl_up(s, dd);
            if (lane >= dd) s += t;
        }
        if (lane == 63) warp_sums[wid] = s;
        __syncthreads();
        if (tid < 16) {
            int ws = warp_sums[tid];
            #pragma unroll
            for (int dd = 1; dd < 16; dd <<= 1) {
                int t = __shfl_up(ws, dd);
                if (tid >= dd) ws += t;
            }
            warp_sums[tid] = ws;
        }
        __syncthreads();
        int excl = s_carry + (wid ? warp_sums[wid - 1] : 0) + (s - tsum);
        int o[VPT];
        #pragma unroll
        for (int k = 0; k < VPT; ++k) { o[k] = excl; excl += v[k]; }
        if (full) {
            #pragma unroll
            for (int qq = 0; qq < VPT / 4; ++qq) {
                ((int4*)o0)[iC * (VPT / 4) + qq] = *(int4*)&o[qq * 4];
                if (o1) ((int4*)o1)[iC * (VPT / 4) + qq] = *(int4*)&o[qq * 4];
            }
        } else {
            for (int k = 0; k < VPT; ++k)
                if (iC * VPT + k < n) {
                    o0[iC * VPT + k] = o[k];
                    if (o1) o1[iC * VPT + k] = o[k];
                }
        }
        __syncthreads();
        if (tid == 0) s_carry = s_carry + warp_sums[15];
        __syncthreads();
    }
}

__global__ void scatter_kernel(const int* __restrict__ ei,
                               int* __restrict__ cur_s, int* __restrict__ cur_d,
                               int2* __restrict__ e2,
                               int* __restrict__ ss2, int E, int Et)
{
    int g = blockIdx.x * blockDim.x + threadIdx.x;
    if (g >= Et) return;
    int src, dst;
    if (g < E) { src = ei[g]; dst = ei[E + g]; }
    else       { src = dst = g - E; }
    int ps = atomicAdd(&cur_s[src], 1);
    e2[ps] = make_int2(src, dst);
    int pd = atomicAdd(&cur_d[dst], 1);
    ss2[pd] = src;
}

// ---------------------------------------------------------------------------
// K2: denom, atomic-free, thread-per-(dst,head): 33 consecutive threads share
// one dst, so ss2 reads broadcast and a_src reads coalesce to 132B rows (the
// old wave-per-dst shape idled 31/64 lanes). a_src gather software-pipelined
// one deep. Writes interleaved float2 {a_dst, 1/(denom+eps)} fully coalesced.
// ---------------------------------------------------------------------------
__global__ __launch_bounds__(256) void denom_kernel(
    const int* __restrict__ off_d, const int* __restrict__ ss2,
    const float* __restrict__ a_src, const float* __restrict__ a_dstc,
    float* __restrict__ ad2, int N, int Et)
{
    int g = blockIdx.x * blockDim.x + threadIdx.x;
    if (g >= N * H_HEADS) return;
    const int d = g / H_HEADS, h = g - d * H_HEADS;
    const int beg = off_d[d];
    const int end = (d + 1 < N) ? off_d[d + 1] : Et;
    const float ad = a_dstc[g];
    float acc = 0.f;
    float vcur = a_src[(size_t)ss2[beg] * H_HEADS + h];   // deg >= 1 (self loop)
    for (int e = beg; e < end; ++e) {
        float vnxt = 0.f;
        if (e + 1 < end) vnxt = a_src[(size_t)ss2[e + 1] * H_HEADS + h];
        float v = vcur + ad;
        v = v > 0.f ? v : NEG_SLOPE * v;
        acc += __expf(v);
        vcur = vnxt;
    }
    ((float2*)ad2)[g] = make_float2(ad, 1.0f / (acc + 1e-16f));
}

// ---------------------------------------------------------------------------
// K3: 64 src-sorted edges/block. Round-5 showed VGPR=28 starved the kernel
// of in-flight loads (VALU 43%, HBM 28%, nothing saturated). Both phases now
// REGISTER-STAGE their loads (phase 1: 9 (ad2,a_src) pairs; phase 2: all 33
// uint2 h-words) so every lane has its full load set in flight before any
// dependent compute; launch_bounds(256,4) allows the ~110 VGPRs.
// ---------------------------------------------------------------------------
#define EPB 64
__global__ __launch_bounds__(256, 4) void aggregate_kernel(
    const int2* __restrict__ e2,
    const float* __restrict__ a_src, const float* __restrict__ ad2,
    const unsigned short* __restrict__ hb,
    float* __restrict__ out, int N, int Et)
{
    __shared__ int   s_src[EPB], s_dst[EPB];
    __shared__ float s_alpha[EPB][H_HEADS];

    // bijective XCD-chunked block swizzle (m204 formula)
    const int nwg = gridDim.x;
    const int q = nwg >> 3, r = nwg & 7;
    const int xcd = blockIdx.x & 7, idx = blockIdx.x >> 3;
    const int bid = (xcd < r ? xcd * (q + 1) : r * (q + 1) + (xcd - r) * q) + idx;

    const int tid = threadIdx.x;
    const int e0  = bid * EPB;
    const size_t segN = (size_t)N * 48;

    if (tid < EPB) {
        int e = e0 + tid;
        int2 v = (e < Et) ? e2[e] : make_int2(0, 0);
        s_src[tid] = v.x; s_dst[tid] = v.y;
    }
    __syncthreads();

    // phase 1: 64x33 = 2112 items = 8 full rounds + 64; loads staged first.
    // (invalid tail edges use src/dst 0 -> safe loads; results never used)
    float2 di[9]; float as[9];
    #pragma unroll
    for (int rr = 0; rr < 8; ++rr) {
        int i = tid + rr * 256;
        int el = i / H_HEADS, hd = i - el * H_HEADS;
        di[rr] = ((const float2*)ad2)[(size_t)s_dst[el] * H_HEADS + hd];
        as[rr] = a_src[(size_t)s_src[el] * H_HEADS + hd];
    }
    if (tid < 64) {
        int i = 2048 + tid;
        int el = i / H_HEADS, hd = i - el * H_HEADS;
        di[8] = ((const float2*)ad2)[(size_t)s_dst[el] * H_HEADS + hd];
        as[8] = a_src[(size_t)s_src[el] * H_HEADS + hd];
    }
    #pragma unroll
    for (int rr = 0; rr < 8; ++rr) {
        int i = tid + rr * 256;
        int el = i / H_HEADS, hd = i - el * H_HEADS;
        float v = as[rr] + di[rr].x;
        v = v > 0.f ? v : NEG_SLOPE * v;
        s_alpha[el][hd] = __expf(v) * di[rr].y;
    }
    if (tid < 64) {
        int i = 2048 + tid;
        int el = i / H_HEADS, hd = i - el * H_HEADS;
        float v = as[8] + di[8].x;
        v = v > 0.f ? v : NEG_SLOPE * v;
        s_alpha[el][hd] = __expf(v) * di[8].y;
    }
    __syncthreads();

    // phase 2: one edge per thread-quad, 4 channels per lane; all 33 uint2
    // loads staged into registers before the FMA block.
    const int el = tid >> 2, cq = tid & 3;
    const int src = s_src[el];
    const unsigned short* hp = hb + (size_t)src * 48 + cq * 4;
    uint2 w[33];
    #pragma unroll
    for (int j = 0; j < JG; ++j) {
        const unsigned short* pj = hp + (size_t)j * segN;
        w[3 * j + 0] = *(const uint2*)(pj);
        w[3 * j + 1] = *(const uint2*)(pj + 16);
        w[3 * j + 2] = *(const uint2*)(pj + 32);
    }
    float a0 = 0.f, a1 = 0.f, a2 = 0.f, a3 = 0.f;
    #pragma unroll
    for (int j = 0; j < JG; ++j) {
        float l0 = s_alpha[el][3 * j + 0];
        float l1 = s_alpha[el][3 * j + 1];
        float l2 = s_alpha[el][3 * j + 2];
        a0 += l0 * bflo(w[3*j].x) + l1 * bflo(w[3*j+1].x) + l2 * bflo(w[3*j+2].x);
        a1 += l0 * bfhi(w[3*j].x) + l1 * bfhi(w[3*j+1].x) + l2 * bfhi(w[3*j+2].x);
        a2 += l0 * bflo(w[3*j].y) + l1 * bflo(w[3*j+1].y) + l2 * bflo(w[3*j+2].y);
        a3 += l0 * bfhi(w[3*j].y) + l1 * bfhi(w[3*j+1].y) + l2 * bfhi(w[3*j+2].y);
    }

    // shfl-repack: instr qx covers 4 edges x 16 contiguous channels (64B)
    const int lane  = tid & 63;
    const int wbase = (tid >> 6) * 16;       // first edge of this wave
    #pragma unroll
    for (int qx = 0; qx < 4; ++qx) {
        int S = 16 * qx + ((lane >> 4) << 2) + ((lane & 15) >> 2);
        float s0 = __shfl(a0, S), s1 = __shfl(a1, S);
        float s2 = __shfl(a2, S), s3 = __shfl(a3, S);
        float v = (lane & 2) ? ((lane & 1) ? s3 : s2)
                             : ((lane & 1) ? s1 : s0);
        int elT = wbase + qx * 4 + (lane >> 4);
        if (e0 + elT < Et)
            atomicAdd(&out[s_dst[elT] * C_CH + (lane & 15)], v);
    }
}

// K4: out = tanh(out/H + bias), in place
__global__ void finalize_kernel(float* __restrict__ out,
                                const float* __restrict__ bias, int total)
{
    int g = blockIdx.x * blockDim.x + threadIdx.x;
    if (g >= total) return;
    out[g] = tanhf(out[g] * (1.0f / 33.0f) + bias[g & 15]);
}

// ---------------------------------------------------------------------------
extern "C" void kernel_launch(void* const* d_in, const int* in_sizes, int n_in,
                              void* d_out, int out_size, void* d_ws, size_t ws_size,
                              hipStream_t stream)
{
    const float* x       = (const float*)d_in[0];
    const int*   ei      = (const int*)  d_in[1];
    const float* W       = (const float*)d_in[2];
    const float* att_src = (const float*)d_in[3];
    const float* att_dst = (const float*)d_in[4];
    const float* bias    = (const float*)d_in[5];
    float* out = (float*)d_out;

    const int N  = in_sizes[0] / F_IN;   // 50000
    const int E  = in_sizes[1] / 2;      // 320000
    const int Et = E + N;                // with self loops

    // workspace layout (all 16B-aligned for these sizes)
    unsigned short* hb = (unsigned short*)d_ws;          // 11 segments [N][48]
    float* a_src  = (float*)(hb + (size_t)N * HC);       // [N][33]
    float* a_dstc = a_src + (size_t)N * H_HEADS;         // [N][33] compact a_dst
    float* ad2    = a_dstc + (size_t)N * H_HEADS;        // float2[N][33] a_dst|inv
    int2*  e2     = (int2*)(ad2 + (size_t)N * 66);       // [Et] (src,dst)
    int*   ss2    = (int*)(e2 + Et);
    int*   hist_s = ss2 + Et;
    int*   hist_d = hist_s + N;
    int*   cur_s  = hist_d + N;
    int*   cur_d  = cur_s + N;
    int*   off_d  = cur_d + N;
    unsigned short* Wt = (unsigned short*)(off_d + N);   // [624][128]

    // prep: Wt build + zero hist_s/hist_d (2N ints) + zero out (out_size f32)
    const int nz1 = (2 * N) / 4;
    const int nz2 = out_size / 4;
    const int prepTot = PW2 + nz1 + nz2;
    prep_kernel<<<(prepTot + 255) / 256, 256, 0, stream>>>(
        W, att_src, att_dst, Wt, (int4*)hist_s, nz1, (float4*)out, nz2);

    gemm_att_kernel<<<(N + 63) / 64, 256, 0, stream>>>(x, Wt, hb, a_src, a_dstc, N);

    hist_kernel<<<(Et + 255) / 256, 256, 0, stream>>>(ei, hist_s, hist_d, E, Et);
    scan_kernel<<<2, 1024, 0, stream>>>(hist_s, cur_s, hist_d, cur_d, off_d, N);
    scatter_kernel<<<(Et + 255) / 256, 256, 0, stream>>>(ei, cur_s, cur_d,
                                                         e2, ss2, E, Et);

    denom_kernel<<<(N * H_HEADS + 255) / 256, 256, 0, stream>>>(
        off_d, ss2, a_src, a_dstc, ad2, N, Et);

    aggregate_kernel<<<(Et + EPB - 1) / EPB, 256, 0, stream>>>(
        e2, a_src, ad2, hb, out, N, Et);

    int totO = N * C_CH;
    finalize_kernel<<<(totO + 255) / 256, 256, 0, stream>>>(out, bias, totO);
}

// Round 7
// 257.248 us; speedup vs baseline: 1.1995x; 1.1995x over previous
//
#include <hip/hip_runtime.h>
#include <math.h>

#define H_HEADS 33
#define C_CH    16
#define HC      528      // H_HEADS * C_CH
#define JG      11       // head groups of 3 (48 cols each) for h
#define JGT     13       // + 2 groups: att_src logits, att_dst logits
#define F_IN    128
#define NEG_SLOPE 0.2f

typedef short  bf16x8  __attribute__((ext_vector_type(8)));
typedef float  floatx4 __attribute__((ext_vector_type(4)));

__device__ inline unsigned short f2bf(float f) {   // RNE float->bf16
    unsigned int u = __float_as_uint(f);
    unsigned int r = u + 0x7fffu + ((u >> 16) & 1u);
    return (unsigned short)(r >> 16);
}
__device__ inline float bflo(unsigned int u) {
    return __uint_as_float(u << 16);
}
__device__ inline float bfhi(unsigned int u) {
    return __uint_as_float(u & 0xffff0000u);
}

// ---------------------------------------------------------------------------
// K0: prep. (a) Wt[0..527] = bf16(W^T); (b) rows 528..623 = attention-logit
// GEMM columns (row 528+h: Ws[k,h]=sum_c W[k][h*16+c]*att_src[h][c]; 576+h
// with att_dst); (c) zero out; (d) edge histograms by src and dst (hist
// arrays are zeroed by a preceding memset — cannot zero+atomic in one
// kernel without a race).
// ---------------------------------------------------------------------------
#define PW1 (F_IN * HC)        // 67584
#define PW2 (PW1 + 96 * F_IN)  // 79872
__global__ void prep_kernel(const float* __restrict__ W,
                            const float* __restrict__ att_src,
                            const float* __restrict__ att_dst,
                            unsigned short* __restrict__ Wt,
                            float4* __restrict__ zout, int nzo,
                            const int* __restrict__ ei,
                            int* __restrict__ hist_s, int* __restrict__ hist_d,
                            int E, int Et)
{
    int g = blockIdx.x * blockDim.x + threadIdx.x;
    if (g < PW1) {
        int k = g / HC, n = g % HC;
        Wt[n * F_IN + k] = f2bf(W[g]);
    } else if (g < PW2) {
        int gg = g - PW1;
        int nl = gg >> 7, k = gg & 127;
        int grp = nl / 48, h = nl % 48;
        float v = 0.f;
        if (h < H_HEADS) {
            const float* att = grp ? att_dst : att_src;
            const float* wr  = W + (size_t)k * HC + h * C_CH;
            #pragma unroll
            for (int c = 0; c < C_CH; ++c) v += wr[c] * att[h * C_CH + c];
        }
        Wt[(size_t)(HC + nl) * F_IN + k] = f2bf(v);
    } else {
        int z = g - PW2;
        if (z < nzo) {
            zout[z] = make_float4(0.f, 0.f, 0.f, 0.f);
        } else {
            int e = z - nzo;
            if (e < Et) {
                int src, dst;
                if (e < E) { src = ei[e]; dst = ei[E + e]; }
                else       { src = dst = e - E; }
                atomicAdd(&hist_s[src], 1);
                atomicAdd(&hist_d[dst], 1);
            }
        }
    }
}

// ---------------------------------------------------------------------------
// K1: h = x @ W via MFMA 16x16x32 bf16 (round-5 LDS structure restored —
// round-6's no-LDS variant failed: compiler allocated 32 VGPRs and
// serialized the 12 B loads into a latency chain).
// NEW: As/Bs share one LDS buffer. As (64x136, 17.4KB) is dead once the A
// fragments are extracted to registers in the prologue, so Bs (48x136)
// overlays it: LDS 30.7KB -> 17.4KB, blocks/CU 5 -> 8 (32-wave cap), giving
// the TLP to hide the register-double-buffered Bs prefetch latency.
// Groups 0..10 -> hb column-blocked [j][row][48]; 11 -> a_src; 12 -> a_dstc.
// ---------------------------------------------------------------------------
#define LDA 136
__global__ __launch_bounds__(256) void gemm_att_kernel(
    const float* __restrict__ x, const unsigned short* __restrict__ Wt,
    unsigned short* __restrict__ hb,
    float* __restrict__ a_src, float* __restrict__ a_dstc, int N)
{
    __shared__ unsigned short U[64 * LDA];   // As (prologue) then Bs (loop)
    unsigned short (*As)[LDA] = (unsigned short (*)[LDA])U;
    unsigned short (*Bs)[LDA] = (unsigned short (*)[LDA])U;

    const int tid  = threadIdx.x;
    const int lane = tid & 63;
    const int wave = tid >> 6;
    const int lm   = lane & 15;
    const int kc   = lane >> 4;
    const int m0   = blockIdx.x * 64;
    const size_t segN = (size_t)N * 48;

    // stage As from f32 x, converting: 64 rows x 32 float4 chunks
    for (int e = tid; e < 64 * 32; e += 256) {
        int r = e >> 5, c = e & 31;
        int gr = m0 + r;
        float4 v = (gr < N) ? ((const float4*)(x + (size_t)gr * F_IN))[c]
                            : make_float4(0.f, 0.f, 0.f, 0.f);
        unsigned int lo = (unsigned int)f2bf(v.x) | ((unsigned int)f2bf(v.y) << 16);
        unsigned int hi = (unsigned int)f2bf(v.z) | ((unsigned int)f2bf(v.w) << 16);
        *(uint2*)&As[r][c * 4] = make_uint2(lo, hi);
    }

    // prefetch j=0 B-tile into registers (Wt rows are contiguous uint4s)
    const uint4* wp = (const uint4*)Wt;
    uint4 rb0 = wp[tid], rb1 = wp[tid + 256], rb2 = wp[tid + 512];

    __syncthreads();

    // A fragments to registers; As LDS space is dead after this (barrier at
    // the top of the j-loop orders these reads before the Bs overwrite)
    const int arow = wave * 16 + lm;
    bf16x8 afrag[4];
    #pragma unroll
    for (int ks = 0; ks < 4; ++ks)
        afrag[ks] = *(const bf16x8*)&As[arow][ks * 32 + kc * 8];

    #pragma unroll 1
    for (int j = 0; j < JGT; ++j) {
        __syncthreads();   // prev iter's Bs reads (and prologue As reads) done
        *(uint4*)&Bs[tid >> 4][(tid & 15) * 8] = rb0;
        { int e = tid + 256; *(uint4*)&Bs[e >> 4][(e & 15) * 8] = rb1; }
        { int e = tid + 512; *(uint4*)&Bs[e >> 4][(e & 15) * 8] = rb2; }
        if (j + 1 < JGT) {
            int b = (j + 1) * 768;
            rb0 = wp[b + tid]; rb1 = wp[b + tid + 256]; rb2 = wp[b + tid + 512];
        }
        __syncthreads();

        floatx4 acc[3] = {};
        #pragma unroll
        for (int ks = 0; ks < 4; ++ks) {
            #pragma unroll
            for (int t = 0; t < 3; ++t) {
                bf16x8 b = *(const bf16x8*)&Bs[t * 16 + lm][ks * 32 + kc * 8];
                acc[t] = __builtin_amdgcn_mfma_f32_16x16x32_bf16(afrag[ks], b, acc[t], 0, 0, 0);
            }
        }

        // C/D layout: col = lane&15, row = (lane>>4)*4 + reg
        #pragma unroll
        for (int t = 0; t < 3; ++t) {
            #pragma unroll
            for (int rr = 0; rr < 4; ++rr) {
                const int row = m0 + wave * 16 + kc * 4 + rr;
                if (row >= N) continue;
                if (j < JG) {
                    hb[(size_t)j * segN + (size_t)row * 48 + t * 16 + lm] =
                        f2bf(acc[t][rr]);
                } else {
                    const int col = t * 16 + lm;
                    if (col < H_HEADS) {
                        float* dstp = (j == JG) ? a_src : a_dstc;
                        dstp[(size_t)row * H_HEADS + col] = acc[t][rr];
                    }
                }
            }
        }
    }
}

// exclusive scan, 16 elems/thread; grid=2: block0 scans hist_s->cur_s,
// block1 scans hist_d->cur_d+off_d (the two scans run concurrently).
#define VPT 16
__global__ __launch_bounds__(1024) void scan_kernel(
    const int* __restrict__ hist_s, int* __restrict__ cur_s,
    const int* __restrict__ hist_d, int* __restrict__ cur_d,
    int* __restrict__ off_d, int n)
{
    const int* hist = blockIdx.x ? hist_d : hist_s;
    int* o0 = blockIdx.x ? cur_d : cur_s;
    int* o1 = blockIdx.x ? off_d : (int*)nullptr;

    __shared__ int warp_sums[16];
    __shared__ int s_carry;
    const int tid  = threadIdx.x;
    const int lane = tid & 63, wid = tid >> 6;
    if (tid == 0) s_carry = 0;
    __syncthreads();
    const int nC = (n + VPT - 1) / VPT;
    for (int base = 0; base < nC; base += 1024) {
        int iC = base + tid;
        int v[VPT];
        bool full = (iC * VPT + VPT <= n);
        if (full) {
            #pragma unroll
            for (int qq = 0; qq < VPT / 4; ++qq)
                *(int4*)&v[qq * 4] = ((const int4*)hist)[iC * (VPT / 4) + qq];
        } else {
            #pragma unroll
            for (int k = 0; k < VPT; ++k)
                v[k] = (iC * VPT + k < n) ? hist[iC * VPT + k] : 0;
        }
        int tsum = 0;
        #pragma unroll
        for (int k = 0; k < VPT; ++k) tsum += v[k];
        int s = tsum;
        #pragma unroll
        for (int dd = 1; dd < 64; dd <<= 1) {
            int t = __shfl_up(s, dd);
            if (lane >= dd) s += t;
        }
        if (lane == 63) warp_sums[wid] = s;
        __syncthreads();
        if (tid < 16) {
            int ws = warp_sums[tid];
            #pragma unroll
            for (int dd = 1; dd < 16; dd <<= 1) {
                int t = __shfl_up(ws, dd);
                if (tid >= dd) ws += t;
            }
            warp_sums[tid] = ws;
        }
        __syncthreads();
        int excl = s_carry + (wid ? warp_sums[wid - 1] : 0) + (s - tsum);
        int o[VPT];
        #pragma unroll
        for (int k = 0; k < VPT; ++k) { o[k] = excl; excl += v[k]; }
        if (full) {
            #pragma unroll
            for (int qq = 0; qq < VPT / 4; ++qq) {
                ((int4*)o0)[iC * (VPT / 4) + qq] = *(int4*)&o[qq * 4];
                if (o1) ((int4*)o1)[iC * (VPT / 4) + qq] = *(int4*)&o[qq * 4];
            }
        } else {
            for (int k = 0; k < VPT; ++k)
                if (iC * VPT + k < n) {
                    o0[iC * VPT + k] = o[k];
                    if (o1) o1[iC * VPT + k] = o[k];
                }
        }
        __syncthreads();
        if (tid == 0) s_carry = s_carry + warp_sums[15];
        __syncthreads();
    }
}

__global__ void scatter_kernel(const int* __restrict__ ei,
                               int* __restrict__ cur_s, int* __restrict__ cur_d,
                               int2* __restrict__ e2,
                               int* __restrict__ ss2, int E, int Et)
{
    int g = blockIdx.x * blockDim.x + threadIdx.x;
    if (g >= Et) return;
    int src, dst;
    if (g < E) { src = ei[g]; dst = ei[E + g]; }
    else       { src = dst = g - E; }
    int ps = atomicAdd(&cur_s[src], 1);
    e2[ps] = make_int2(src, dst);
    int pd = atomicAdd(&cur_d[dst], 1);
    ss2[pd] = src;
}

// ---------------------------------------------------------------------------
// K2: denom, atomic-free, thread-per-(dst,head): 33 consecutive threads share
// one dst, so ss2 reads broadcast and a_src reads coalesce to 132B rows.
// a_src gather software-pipelined one deep. Writes interleaved float2
// {a_dst, 1/(denom+eps)} fully coalesced.
// ---------------------------------------------------------------------------
__global__ __launch_bounds__(256) void denom_kernel(
    const int* __restrict__ off_d, const int* __restrict__ ss2,
    const float* __restrict__ a_src, const float* __restrict__ a_dstc,
    float* __restrict__ ad2, int N, int Et)
{
    int g = blockIdx.x * blockDim.x + threadIdx.x;
    if (g >= N * H_HEADS) return;
    const int d = g / H_HEADS, h = g - d * H_HEADS;
    const int beg = off_d[d];
    const int end = (d + 1 < N) ? off_d[d + 1] : Et;
    const float ad = a_dstc[g];
    float acc = 0.f;
    float vcur = a_src[(size_t)ss2[beg] * H_HEADS + h];   // deg >= 1 (self loop)
    for (int e = beg; e < end; ++e) {
        float vnxt = 0.f;
        if (e + 1 < end) vnxt = a_src[(size_t)ss2[e + 1] * H_HEADS + h];
        float v = vcur + ad;
        v = v > 0.f ? v : NEG_SLOPE * v;
        acc += __expf(v);
        vcur = vnxt;
    }
    ((float2*)ad2)[g] = make_float2(ad, 1.0f / (acc + 1e-16f));
}

// ---------------------------------------------------------------------------
// K3: 64 src-sorted edges/block. Both phases register-stage their loads
// (phase 1: 9 (ad2,a_src) pairs; phase 2: all 33 uint2 h-words) so every
// lane has its full load set in flight before dependent compute;
// launch_bounds(256,4) allows the ~110 VGPRs. shfl-repack gives
// fully-covered 64B atomic lines.
// ---------------------------------------------------------------------------
#define EPB 64
__global__ __launch_bounds__(256, 4) void aggregate_kernel(
    const int2* __restrict__ e2,
    const float* __restrict__ a_src, const float* __restrict__ ad2,
    const unsigned short* __restrict__ hb,
    float* __restrict__ out, int N, int Et)
{
    __shared__ int   s_src[EPB], s_dst[EPB];
    __shared__ float s_alpha[EPB][H_HEADS];

    // bijective XCD-chunked block swizzle (m204 formula)
    const int nwg = gridDim.x;
    const int q = nwg >> 3, r = nwg & 7;
    const int xcd = blockIdx.x & 7, idx = blockIdx.x >> 3;
    const int bid = (xcd < r ? xcd * (q + 1) : r * (q + 1) + (xcd - r) * q) + idx;

    const int tid = threadIdx.x;
    const int e0  = bid * EPB;
    const size_t segN = (size_t)N * 48;

    if (tid < EPB) {
        int e = e0 + tid;
        int2 v = (e < Et) ? e2[e] : make_int2(0, 0);
        s_src[tid] = v.x; s_dst[tid] = v.y;
    }
    __syncthreads();

    // phase 1: 64x33 = 2112 items = 8 full rounds + 64; loads staged first.
    float2 di[9]; float as[9];
    #pragma unroll
    for (int rr = 0; rr < 8; ++rr) {
        int i = tid + rr * 256;
        int el = i / H_HEADS, hd = i - el * H_HEADS;
        di[rr] = ((const float2*)ad2)[(size_t)s_dst[el] * H_HEADS + hd];
        as[rr] = a_src[(size_t)s_src[el] * H_HEADS + hd];
    }
    if (tid < 64) {
        int i = 2048 + tid;
        int el = i / H_HEADS, hd = i - el * H_HEADS;
        di[8] = ((const float2*)ad2)[(size_t)s_dst[el] * H_HEADS + hd];
        as[8] = a_src[(size_t)s_src[el] * H_HEADS + hd];
    }
    #pragma unroll
    for (int rr = 0; rr < 8; ++rr) {
        int i = tid + rr * 256;
        int el = i / H_HEADS, hd = i - el * H_HEADS;
        float v = as[rr] + di[rr].x;
        v = v > 0.f ? v : NEG_SLOPE * v;
        s_alpha[el][hd] = __expf(v) * di[rr].y;
    }
    if (tid < 64) {
        int i = 2048 + tid;
        int el = i / H_HEADS, hd = i - el * H_HEADS;
        float v = as[8] + di[8].x;
        v = v > 0.f ? v : NEG_SLOPE * v;
        s_alpha[el][hd] = __expf(v) * di[8].y;
    }
    __syncthreads();

    // phase 2: one edge per thread-quad, 4 channels per lane; all 33 uint2
    // loads staged into registers before the FMA block.
    const int el = tid >> 2, cq = tid & 3;
    const int src = s_src[el];
    const unsigned short* hp = hb + (size_t)src * 48 + cq * 4;
    uint2 w[33];
    #pragma unroll
    for (int j = 0; j < JG; ++j) {
        const unsigned short* pj = hp + (size_t)j * segN;
        w[3 * j + 0] = *(const uint2*)(pj);
        w[3 * j + 1] = *(const uint2*)(pj + 16);
        w[3 * j + 2] = *(const uint2*)(pj + 32);
    }
    float a0 = 0.f, a1 = 0.f, a2 = 0.f, a3 = 0.f;
    #pragma unroll
    for (int j = 0; j < JG; ++j) {
        float l0 = s_alpha[el][3 * j + 0];
        float l1 = s_alpha[el][3 * j + 1];
        float l2 = s_alpha[el][3 * j + 2];
        a0 += l0 * bflo(w[3*j].x) + l1 * bflo(w[3*j+1].x) + l2 * bflo(w[3*j+2].x);
        a1 += l0 * bfhi(w[3*j].x) + l1 * bfhi(w[3*j+1].x) + l2 * bfhi(w[3*j+2].x);
        a2 += l0 * bflo(w[3*j].y) + l1 * bflo(w[3*j+1].y) + l2 * bflo(w[3*j+2].y);
        a3 += l0 * bfhi(w[3*j].y) + l1 * bfhi(w[3*j+1].y) + l2 * bfhi(w[3*j+2].y);
    }

    // shfl-repack: instr qx covers 4 edges x 16 contiguous channels (64B)
    const int lane  = tid & 63;
    const int wbase = (tid >> 6) * 16;       // first edge of this wave
    #pragma unroll
    for (int qx = 0; qx < 4; ++qx) {
        int S = 16 * qx + ((lane >> 4) << 2) + ((lane & 15) >> 2);
        float s0 = __shfl(a0, S), s1 = __shfl(a1, S);
        float s2 = __shfl(a2, S), s3 = __shfl(a3, S);
        float v = (lane & 2) ? ((lane & 1) ? s3 : s2)
                             : ((lane & 1) ? s1 : s0);
        int elT = wbase + qx * 4 + (lane >> 4);
        if (e0 + elT < Et)
            atomicAdd(&out[s_dst[elT] * C_CH + (lane & 15)], v);
    }
}

// K4: out = tanh(out/H + bias), in place
__global__ void finalize_kernel(float* __restrict__ out,
                                const float* __restrict__ bias, int total)
{
    int g = blockIdx.x * blockDim.x + threadIdx.x;
    if (g >= total) return;
    out[g] = tanhf(out[g] * (1.0f / 33.0f) + bias[g & 15]);
}

// ---------------------------------------------------------------------------
extern "C" void kernel_launch(void* const* d_in, const int* in_sizes, int n_in,
                              void* d_out, int out_size, void* d_ws, size_t ws_size,
                              hipStream_t stream)
{
    const float* x       = (const float*)d_in[0];
    const int*   ei      = (const int*)  d_in[1];
    const float* W       = (const float*)d_in[2];
    const float* att_src = (const float*)d_in[3];
    const float* att_dst = (const float*)d_in[4];
    const float* bias    = (const float*)d_in[5];
    float* out = (float*)d_out;

    const int N  = in_sizes[0] / F_IN;   // 50000
    const int E  = in_sizes[1] / 2;      // 320000
    const int Et = E + N;                // with self loops

    // workspace layout (all 16B-aligned for these sizes)
    unsigned short* hb = (unsigned short*)d_ws;          // 11 segments [N][48]
    float* a_src  = (float*)(hb + (size_t)N * HC);       // [N][33]
    float* a_dstc = a_src + (size_t)N * H_HEADS;         // [N][33] compact a_dst
    float* ad2    = a_dstc + (size_t)N * H_HEADS;        // float2[N][33] a_dst|inv
    int2*  e2     = (int2*)(ad2 + (size_t)N * 66);       // [Et] (src,dst)
    int*   ss2    = (int*)(e2 + Et);
    int*   hist_s = ss2 + Et;
    int*   hist_d = hist_s + N;
    int*   cur_s  = hist_d + N;
    int*   cur_d  = cur_s + N;
    int*   off_d  = cur_d + N;
    unsigned short* Wt = (unsigned short*)(off_d + N);   // [624][128]

    // zero hist_s+hist_d before prep (prep does hist atomics)
    hipMemsetAsync(hist_s, 0, 2 * (size_t)N * sizeof(int), stream);

    const int nzo = out_size / 4;        // out zero in float4s
    const int prepTot = PW2 + nzo + Et;
    prep_kernel<<<(prepTot + 255) / 256, 256, 0, stream>>>(
        W, att_src, att_dst, Wt, (float4*)out, nzo, ei, hist_s, hist_d, E, Et);

    gemm_att_kernel<<<(N + 63) / 64, 256, 0, stream>>>(x, Wt, hb, a_src, a_dstc, N);

    scan_kernel<<<2, 1024, 0, stream>>>(hist_s, cur_s, hist_d, cur_d, off_d, N);
    scatter_kernel<<<(Et + 255) / 256, 256, 0, stream>>>(ei, cur_s, cur_d,
                                                         e2, ss2, E, Et);

    denom_kernel<<<(N * H_HEADS + 255) / 256, 256, 0, stream>>>(
        off_d, ss2, a_src, a_dstc, ad2, N, Et);

    aggregate_kernel<<<(Et + EPB - 1) / EPB, 256, 0, stream>>>(
        e2, a_src, ad2, hb, out, N, Et);

    int totO = N * C_CH;
    finalize_kernel<<<(totO + 255) / 256, 256, 0, stream>>>(out, bias, totO);
}